// Round 3
// baseline (1525.779 us; speedup 1.0000x reference)
//
#include <hip/hip_runtime.h>

#define Nn 100000
#define INC 256
#define OC 40
#define GEL 5242880u               // element offset of g2 = 131072*40 (18-bit rid addressing)
#define NB 782                     // buckets: src>>7, 128 rows each
#define CAP 7040                   // edges per bucket capacity (mean 6144, ~11 sigma)
#define CHUNK 4096                 // edges per partition block
#define OVFCAP 65536
#define BSTRIDE 264                // LDS stride (bf16) for M tile
#define APITCH 41                  // gather LDS accumulator pitch (floats) — 41 ≡ 9 mod 32, bank-uniform

// ---- workspace layout (bytes) ----
#define MP_OFF   0                        // bf16 M: 128*256*2 = 65536 (slot 131072)
#define G_OFF    131072                   // bf16 g[2][131072][40] = 20,971,520 B
#define GCUR_OFF (G_OFF + 20971520)       // NB ints = 3128 B (slot 3200)
#define OVFC_OFF (GCUR_OFF + 3200)        // 1 int (16 B slot)
#define OVFL_OFF (OVFC_OFF + 16)          // OVFCAP * 12 B
#define PAY_OFF  (OVFL_OFF + OVFCAP*12)   // NB*CAP*8 B = 44,042,240 B (16B aligned)

typedef __attribute__((ext_vector_type(8))) short bf16x8;
typedef __attribute__((ext_vector_type(4))) float f32x4;

__device__ __forceinline__ unsigned short f2bf(float f) {
    unsigned b = __float_as_uint(f);
    b += 0x7FFFu + ((b >> 16) & 1u);     // RNE
    return (unsigned short)(b >> 16);
}
__device__ __forceinline__ float bf2f(unsigned short u) {
    return __uint_as_float(((unsigned)u) << 16);
}

// Mb[128][256] bf16
__global__ void make_M(const float* __restrict__ fc1_w,
                       const float* __restrict__ fc_out_w,
                       unsigned short* __restrict__ Mb) {
    int j = blockIdx.x;   // 0..127
    int k = threadIdx.x;  // 0..255
    float acc = 0.f;
    if (j < 120) {
        int i = j / 40, o = j - i * 40;
        const float* wrow = fc_out_w + o * 192 + i * 64;
#pragma unroll 8
        for (int t = 0; t < 64; ++t)
            acc = fmaf(wrow[t], fc1_w[t * 256 + k], acc);
    }
    Mb[j * 256 + k] = (j < 120) ? f2bf(acc) : (unsigned short)0;
}

// MFMA bf16 GEMM: block = 128 rows x 120 cols, 8 waves (16 rows each).
__global__ __launch_bounds__(512, 4) void gemm_mfma(
    const float* __restrict__ x, const unsigned short* __restrict__ Mb,
    const float* __restrict__ bias, float* __restrict__ out,
    unsigned short* __restrict__ g) {
    __shared__ unsigned short mlds[120 * BSTRIDE];
    const int tid = threadIdx.x;
    const int w = tid >> 6;
    const int l = tid & 63;
    const int lane15 = l & 15;
    const int quad = l >> 4;

    for (int i = tid; i < 3840; i += 512) {
        int r = i >> 5;
        int k8 = (i & 31) * 8;
        uint4 v = *(const uint4*)(Mb + r * 256 + k8);
        *(uint4*)(mlds + r * BSTRIDE + k8) = v;
    }
    __syncthreads();

    const int arow = blockIdx.x * 128 + w * 16 + lane15;
    const bool rok = arow < Nn;
    const float* xp = x + (size_t)arow * INC + quad * 8;

    f32x4 acc[8];
#pragma unroll
    for (int c = 0; c < 8; ++c) acc[c] = (f32x4){0.f, 0.f, 0.f, 0.f};

    float4 pa[3], pb_[3];
#pragma unroll
    for (int p = 0; p < 2; ++p) {
        pa[p] = make_float4(0, 0, 0, 0); pb_[p] = make_float4(0, 0, 0, 0);
        if (rok) { pa[p] = *(const float4*)(xp + p * 32); pb_[p] = *(const float4*)(xp + p * 32 + 4); }
    }

#pragma unroll
    for (int kt = 0; kt < 8; ++kt) {
        const int nb = (kt + 2) % 3;
        if (kt + 2 < 8) {
            pa[nb] = make_float4(0, 0, 0, 0); pb_[nb] = make_float4(0, 0, 0, 0);
            if (rok) {
                pa[nb] = *(const float4*)(xp + (kt + 2) * 32);
                pb_[nb] = *(const float4*)(xp + (kt + 2) * 32 + 4);
            }
        }
        const int cu = kt % 3;
        bf16x8 af;
        af[0] = (short)f2bf(pa[cu].x); af[1] = (short)f2bf(pa[cu].y);
        af[2] = (short)f2bf(pa[cu].z); af[3] = (short)f2bf(pa[cu].w);
        af[4] = (short)f2bf(pb_[cu].x); af[5] = (short)f2bf(pb_[cu].y);
        af[6] = (short)f2bf(pb_[cu].z); af[7] = (short)f2bf(pb_[cu].w);
        const unsigned short* bbase = mlds + kt * 32 + quad * 8 + lane15 * BSTRIDE;
#pragma unroll
        for (int ct = 0; ct < 8; ++ct) {
            if (ct * 16 >= 120) break;
            bf16x8 bf = *(const bf16x8*)(bbase + ct * 16 * BSTRIDE);
            acc[ct] = __builtin_amdgcn_mfma_f32_16x16x32_bf16(af, bf, acc[ct], 0, 0, 0);
        }
    }

#pragma unroll
    for (int ct = 0; ct < 8; ++ct) {
        int col = ct * 16 + lane15;
        if (col >= 120) continue;
        int ib = col / 40;
        int cc = col - ib * 40;
        float badd = (ib == 0) ? bias[cc] : 0.f;
#pragma unroll
        for (int reg = 0; reg < 4; ++reg) {
            int gr = blockIdx.x * 128 + w * 16 + quad * 4 + reg;
            if (gr >= Nn) continue;
            float v = acc[ct][reg] + badd;
            if (ib == 0) out[gr * 40 + cc] = v;
            else g[(unsigned)(ib - 1) * GEL + (unsigned)gr * 40u + cc] = f2bf(v);
        }
    }
}

// Partition: chunk-local LDS sort into 128-row buckets (src>>7), coalesced
// per-bucket run writes (R0 structure — scattered sub-line writes are 16x
// amplified, proven in R2).  Entry: {d | gbit<<17 | (s&127)<<18, v_f32}.
__global__ __launch_bounds__(1024, 8) void partition(
    const int* __restrict__ s1, const int* __restrict__ d1, const float* __restrict__ v1, int E1,
    const int* __restrict__ s2, const int* __restrict__ d2, const float* __restrict__ v2, int E2,
    int* __restrict__ gcur, uint2* __restrict__ payload,
    int* __restrict__ ovf_cnt, unsigned* __restrict__ ovf) {
    __shared__ int cnt[NB];
    __shared__ int loff[NB + 1];
    __shared__ int gbase[NB];
    __shared__ int scanbuf[1024];
    __shared__ uint2 pay[CHUNK];
    __shared__ unsigned short dest16[CHUNK];

    const int t = threadIdx.x;
    const int Etot = E1 + E2;
    const int e0 = blockIdx.x * CHUNK;

    for (int i = t; i < NB; i += 1024) cnt[i] = 0;
    __syncthreads();

    int my_b[4]; int my_rank[4]; unsigned my_p[4]; float my_v[4]; bool my_ok[4];
#pragma unroll
    for (int j = 0; j < 4; ++j) {
        int e = e0 + j * 1024 + t;
        my_ok[j] = (e < Etot);
        if (my_ok[j]) {
            int s, d; float v; unsigned gbit;
            if (e < E1) { s = s1[e]; d = d1[e]; v = v1[e]; gbit = 0u; }
            else { int e2 = e - E1; s = s2[e2]; d = d2[e2]; v = v2[e2]; gbit = 1u; }
            my_b[j] = s >> 7;
            my_p[j] = (unsigned)d | (gbit << 17) | (((unsigned)s & 127u) << 18);
            my_v[j] = v;
            my_rank[j] = atomicAdd(&cnt[my_b[j]], 1);
        }
    }
    __syncthreads();

    // exclusive scan of cnt[NB] (NB < 1024)
    int c = (t < NB) ? cnt[t] : 0;
    scanbuf[t] = c;
    __syncthreads();
    for (int off = 1; off < 1024; off <<= 1) {
        int v = (t >= off) ? scanbuf[t - off] : 0;
        __syncthreads();
        scanbuf[t] += v;
        __syncthreads();
    }
    if (t < NB) loff[t] = scanbuf[t] - c;
    if (t == 1023) loff[NB] = scanbuf[1023];
    __syncthreads();

    if (t < NB) {
        int cc = cnt[t];
        gbase[t] = cc ? atomicAdd(&gcur[t], cc) : 0;
    }
    __syncthreads();

#pragma unroll
    for (int j = 0; j < 4; ++j) {
        if (my_ok[j]) {
            int lp = loff[my_b[j]] + my_rank[j];
            pay[lp] = make_uint2(my_p[j], __float_as_uint(my_v[j]));
            dest16[lp] = (unsigned short)my_b[j];
        }
    }
    __syncthreads();

    int tot = loff[NB];
    for (int i = t; i < tot; i += 1024) {
        int b = dest16[i];
        int go = gbase[b] + (i - loff[b]);
        if (go < CAP) payload[(size_t)b * CAP + go] = pay[i];
        else {
            int op = atomicAdd(ovf_cnt, 1);
            if (op < OVFCAP) {
                unsigned px = pay[i].x;
                ovf[3 * op] = ((unsigned)b << 7) | ((px >> 18) & 127u);
                ovf[3 * op + 1] = px;
                ovf[3 * op + 2] = pay[i].y;
            }
        }
    }
}

// Gather: one block per 128-row bucket.  NO sort: 128x40 f32 accumulator in
// LDS, single coalesced payload sweep, 5 lanes per edge (16B g-load each),
// ds_add_f32 resolves rows.  g-loads stream continuously — no serial phase.
__global__ __launch_bounds__(640, 8) void bucket_gather(
    const int* __restrict__ gcur, const uint2* __restrict__ payload,
    const unsigned short* __restrict__ g, float* __restrict__ out) {
    __shared__ float accum[128 * APITCH];   // 20,992 B

    const int t = threadIdx.x;
    const int b = blockIdx.x;

    for (int i = t; i < 128 * APITCH; i += 640) accum[i] = 0.f;
    int n = gcur[b];
    n = (n < CAP) ? n : CAP;
    __syncthreads();

    const uint2* pb = payload + (size_t)b * CAP;
    const int grp = t / 5;                 // 0..127 edge streams
    const int q8 = (t - grp * 5) * 8;      // 0,8,16,24,32

    // 2-deep software pipeline: next edge's payload+g-load in flight while
    // current edge accumulates.
    int i = grp;
    uint2 pc; uint4 uc;
    if (i < n) {
        pc = pb[i];
        uc = *(const uint4*)(g + (pc.x & 0x3FFFFu) * 40u + q8);
    }
    while (i < n) {
        int j = i + 128;
        uint2 pn; uint4 un;
        if (j < n) {
            pn = pb[j];
            un = *(const uint4*)(g + (pn.x & 0x3FFFFu) * 40u + q8);
        }
        {
            float v = __uint_as_float(pc.y);
            int row = (pc.x >> 18) & 127;
            float* ap = accum + row * APITCH + q8;
            atomicAdd(ap + 0, v * __uint_as_float(uc.x << 16));
            atomicAdd(ap + 1, v * __uint_as_float(uc.x & 0xFFFF0000u));
            atomicAdd(ap + 2, v * __uint_as_float(uc.y << 16));
            atomicAdd(ap + 3, v * __uint_as_float(uc.y & 0xFFFF0000u));
            atomicAdd(ap + 4, v * __uint_as_float(uc.z << 16));
            atomicAdd(ap + 5, v * __uint_as_float(uc.z & 0xFFFF0000u));
            atomicAdd(ap + 6, v * __uint_as_float(uc.w << 16));
            atomicAdd(ap + 7, v * __uint_as_float(uc.w & 0xFFFF0000u));
        }
        pc = pn; uc = un; i = j;
    }
    __syncthreads();

    // write-out: thread t owns (row t/5, cols q8..q8+7); one RMW to out
    const int row = grp;
    const int gr = b * 128 + row;
    if (gr < Nn) {
        const float* ap = accum + row * APITCH + q8;   // not 16B-aligned (pitch 41) — scalar reads
        float s0 = ap[0], s1 = ap[1], s2 = ap[2], s3 = ap[3];
        float s4 = ap[4], s5 = ap[5], s6 = ap[6], s7 = ap[7];
        float* po = out + gr * 40 + q8;
        float4 o0 = *(const float4*)po;
        o0.x += s0; o0.y += s1; o0.z += s2; o0.w += s3;
        *(float4*)po = o0;
        float4 o1 = *(const float4*)(po + 4);
        o1.x += s4; o1.y += s5; o1.z += s6; o1.w += s7;
        *(float4*)(po + 4) = o1;
    }
}

// Slow-path for (expected-zero) bucket overflow.
__global__ __launch_bounds__(256) void ovf_scatter(
    const int* __restrict__ ovf_cnt, const unsigned* __restrict__ ovf,
    const unsigned short* __restrict__ g, float* __restrict__ out) {
    int n = *ovf_cnt;
    n = (n < OVFCAP) ? n : OVFCAP;
    int total = n * 40;
    for (int i = blockIdx.x * 256 + threadIdx.x; i < total; i += 2048) {
        int idx = i / 40, c = i % 40;
        unsigned s = ovf[3 * idx];
        unsigned p = ovf[3 * idx + 1];
        float v = __uint_as_float(ovf[3 * idx + 2]);
        unsigned rid = p & 0x3FFFFu;           // d | gbit<<17 — direct row id
        float gf = bf2f(g[rid * 40u + c]);
        unsafeAtomicAdd(out + s * 40 + c, v * gf);
    }
}

extern "C" void kernel_launch(void* const* d_in, const int* in_sizes, int n_in,
                              void* d_out, int out_size, void* d_ws, size_t ws_size,
                              hipStream_t stream) {
    const float* x        = (const float*)d_in[0];
    const int*   adj_src  = (const int*)d_in[2];
    const int*   adj_dst  = (const int*)d_in[3];
    const float* adj_val  = (const float*)d_in[4];
    const int*   adj2_src = (const int*)d_in[5];
    const int*   adj2_dst = (const int*)d_in[6];
    const float* adj2_val = (const float*)d_in[7];
    const float* fc1_w    = (const float*)d_in[8];
    const float* fc_out_w = (const float*)d_in[9];
    const float* fc_out_b = (const float*)d_in[10];
    float* out = (float*)d_out;

    char* ws = (char*)d_ws;
    unsigned short* Mb      = (unsigned short*)(ws + MP_OFF);
    unsigned short* g       = (unsigned short*)(ws + G_OFF);
    int*            gcur    = (int*)(ws + GCUR_OFF);
    int*            ovf_cnt = (int*)(ws + OVFC_OFF);
    unsigned*       ovf     = (unsigned*)(ws + OVFL_OFF);
    uint2*          payload = (uint2*)(ws + PAY_OFF);

    const int E1 = in_sizes[2];
    const int E2 = in_sizes[5];
    const int Etot = E1 + E2;

    make_M<<<128, 256, 0, stream>>>(fc1_w, fc_out_w, Mb);
    gemm_mfma<<<(Nn + 127) / 128, 512, 0, stream>>>(x, Mb, fc_out_b, out, g);

    hipMemsetAsync(gcur, 0, (OVFC_OFF - GCUR_OFF) + 16, stream);  // gcur + ovf_cnt
    partition<<<(Etot + CHUNK - 1) / CHUNK, 1024, 0, stream>>>(
        adj_src, adj_dst, adj_val, E1, adj2_src, adj2_dst, adj2_val, E2,
        gcur, payload, ovf_cnt, ovf);
    bucket_gather<<<NB, 640, 0, stream>>>(gcur, payload, g, out);
    ovf_scatter<<<8, 256, 0, stream>>>(ovf_cnt, ovf, g, out);
}

// Round 4
// 539.394 us; speedup vs baseline: 2.8287x; 2.8287x over previous
//
#include <hip/hip_runtime.h>

#define Nn 100000
#define INC 256
#define GEL 5242880u               // element offset of g2 = 131072*40 (18-bit rid addressing)
#define NSB 98                     // super-buckets: s>>10 (1024 rows each)
#define SCAP 51456                 // super slice capacity (mean 49152, +10.5 sigma)
#define NCH2 13                    // stage-2 chunks per super
#define SEGW 288                   // per-(chunk,fine) segment capacity (lambda=256, +2 sigma)
#define CREG 4608                  // 16*SEGW — per-chunk output region (>= CHUNK: in-place safe)
#define SREG 59904                 // 13*CREG — uint2 region per super (>= SCAP)
#define CHUNK 4096
#define OVFCAP 32768
#define BSTRIDE 264                // LDS stride (bf16) for M tile

// ---- workspace layout (bytes), total 68,442,384 (65.3 MB, < proven 66.04) ----
#define MP_OFF   0                 // bf16 M: 128*256*2 = 65536
#define G_OFF    65536             // bf16 g[2][131072][40] = 20,971,520
#define SCUR_OFF 21037056          // 98 counters padded to 64 B each = 6400
#define OVFC_OFF 21043456          // 1 int (16 B)
#define OVFL_OFF 21043472          // OVFCAP*12 = 393,216
#define SCNT_OFF 21436688          // 98*13*16 ushort = 40,768 (pad 40,960)
#define PAY_OFF  21477648          // 98*SREG*8 = 46,964,736

typedef __attribute__((ext_vector_type(8))) short bf16x8;
typedef __attribute__((ext_vector_type(4))) float f32x4;

__device__ __forceinline__ unsigned short f2bf(float f) {
    unsigned b = __float_as_uint(f);
    b += 0x7FFFu + ((b >> 16) & 1u);     // RNE
    return (unsigned short)(b >> 16);
}
__device__ __forceinline__ float bf2f(unsigned short u) {
    return __uint_as_float(((unsigned)u) << 16);
}

// 8 bf16 (packed in uint4) FMA into two float4 accumulators.
__device__ __forceinline__ void fma8(float4& a0, float4& a1, uint4 u, float v) {
    a0.x = fmaf(v, __uint_as_float(u.x << 16), a0.x);
    a0.y = fmaf(v, __uint_as_float(u.x & 0xFFFF0000u), a0.y);
    a0.z = fmaf(v, __uint_as_float(u.y << 16), a0.z);
    a0.w = fmaf(v, __uint_as_float(u.y & 0xFFFF0000u), a0.w);
    a1.x = fmaf(v, __uint_as_float(u.z << 16), a1.x);
    a1.y = fmaf(v, __uint_as_float(u.z & 0xFFFF0000u), a1.y);
    a1.z = fmaf(v, __uint_as_float(u.w << 16), a1.z);
    a1.w = fmaf(v, __uint_as_float(u.w & 0xFFFF0000u), a1.w);
}

// Mb[128][256] bf16
__global__ void make_M(const float* __restrict__ fc1_w,
                       const float* __restrict__ fc_out_w,
                       unsigned short* __restrict__ Mb) {
    int j = blockIdx.x;   // 0..127
    int k = threadIdx.x;  // 0..255
    float acc = 0.f;
    if (j < 120) {
        int i = j / 40, o = j - i * 40;
        const float* wrow = fc_out_w + o * 192 + i * 64;
#pragma unroll 8
        for (int t = 0; t < 64; ++t)
            acc = fmaf(wrow[t], fc1_w[t * 256 + k], acc);
    }
    Mb[j * 256 + k] = (j < 120) ? f2bf(acc) : (unsigned short)0;
}

// MFMA bf16 GEMM: block = 128 rows x 120 cols, 8 waves (16 rows each).
__global__ __launch_bounds__(512, 4) void gemm_mfma(
    const float* __restrict__ x, const unsigned short* __restrict__ Mb,
    const float* __restrict__ bias, float* __restrict__ out,
    unsigned short* __restrict__ g) {
    __shared__ unsigned short mlds[120 * BSTRIDE];
    const int tid = threadIdx.x;
    const int w = tid >> 6;
    const int l = tid & 63;
    const int lane15 = l & 15;
    const int quad = l >> 4;

    for (int i = tid; i < 3840; i += 512) {
        int r = i >> 5;
        int k8 = (i & 31) * 8;
        uint4 v = *(const uint4*)(Mb + r * 256 + k8);
        *(uint4*)(mlds + r * BSTRIDE + k8) = v;
    }
    __syncthreads();

    const int arow = blockIdx.x * 128 + w * 16 + lane15;
    const bool rok = arow < Nn;
    const float* xp = x + (size_t)arow * INC + quad * 8;

    f32x4 acc[8];
#pragma unroll
    for (int c = 0; c < 8; ++c) acc[c] = (f32x4){0.f, 0.f, 0.f, 0.f};

    float4 pa[3], pb_[3];
#pragma unroll
    for (int p = 0; p < 2; ++p) {
        pa[p] = make_float4(0, 0, 0, 0); pb_[p] = make_float4(0, 0, 0, 0);
        if (rok) { pa[p] = *(const float4*)(xp + p * 32); pb_[p] = *(const float4*)(xp + p * 32 + 4); }
    }

#pragma unroll
    for (int kt = 0; kt < 8; ++kt) {
        const int nb = (kt + 2) % 3;
        if (kt + 2 < 8) {
            pa[nb] = make_float4(0, 0, 0, 0); pb_[nb] = make_float4(0, 0, 0, 0);
            if (rok) {
                pa[nb] = *(const float4*)(xp + (kt + 2) * 32);
                pb_[nb] = *(const float4*)(xp + (kt + 2) * 32 + 4);
            }
        }
        const int cu = kt % 3;
        bf16x8 af;
        af[0] = (short)f2bf(pa[cu].x); af[1] = (short)f2bf(pa[cu].y);
        af[2] = (short)f2bf(pa[cu].z); af[3] = (short)f2bf(pa[cu].w);
        af[4] = (short)f2bf(pb_[cu].x); af[5] = (short)f2bf(pb_[cu].y);
        af[6] = (short)f2bf(pb_[cu].z); af[7] = (short)f2bf(pb_[cu].w);
        const unsigned short* bbase = mlds + kt * 32 + quad * 8 + lane15 * BSTRIDE;
#pragma unroll
        for (int ct = 0; ct < 8; ++ct) {
            if (ct * 16 >= 120) break;
            bf16x8 bf = *(const bf16x8*)(bbase + ct * 16 * BSTRIDE);
            acc[ct] = __builtin_amdgcn_mfma_f32_16x16x32_bf16(af, bf, acc[ct], 0, 0, 0);
        }
    }

#pragma unroll
    for (int ct = 0; ct < 8; ++ct) {
        int col = ct * 16 + lane15;
        if (col >= 120) continue;
        int ib = col / 40;
        int cc = col - ib * 40;
        float badd = (ib == 0) ? bias[cc] : 0.f;
#pragma unroll
        for (int reg = 0; reg < 4; ++reg) {
            int gr = blockIdx.x * 128 + w * 16 + quad * 4 + reg;
            if (gr >= Nn) continue;
            float v = acc[ct][reg] + badd;
            if (ib == 0) out[gr * 40 + cc] = v;
            else g[(unsigned)(ib - 1) * GEL + (unsigned)gr * 40u + cc] = f2bf(v);
        }
    }
}

// Stage 1: chunk-local LDS sort into 98 SUPER-buckets (s>>10).  Runs are
// ~42 edges (334 B) -> coalesced, ~1.1x line amplification (vs 21 B runs at
// 1563 buckets).  Entry: {d | gbit<<17 | (s&1023)<<18, v_f32}.
__global__ __launch_bounds__(1024, 8) void partition1(
    const int* __restrict__ s1, const int* __restrict__ d1, const float* __restrict__ v1, int E1,
    const int* __restrict__ s2, const int* __restrict__ d2, const float* __restrict__ v2, int E2,
    int* __restrict__ scur, uint2* __restrict__ sp,
    int* __restrict__ ovf_cnt, unsigned* __restrict__ ovf) {
    __shared__ int cnt[NSB];
    __shared__ int loff[NSB + 1];
    __shared__ int gbase[NSB];
    __shared__ uint2 pay[CHUNK];
    __shared__ unsigned char dest8[CHUNK];

    const int t = threadIdx.x;
    const int Etot = E1 + E2;
    const int e0 = blockIdx.x * CHUNK;

    for (int i = t; i < NSB; i += 1024) cnt[i] = 0;
    __syncthreads();

    int my_b[4]; int my_rank[4]; unsigned my_p[4]; float my_v[4]; bool my_ok[4];
#pragma unroll
    for (int j = 0; j < 4; ++j) {
        int e = e0 + j * 1024 + t;
        my_ok[j] = (e < Etot);
        if (my_ok[j]) {
            int s, d; float v; unsigned gbit;
            if (e < E1) { s = s1[e]; d = d1[e]; v = v1[e]; gbit = 0u; }
            else { int e2 = e - E1; s = s2[e2]; d = d2[e2]; v = v2[e2]; gbit = 1u; }
            my_b[j] = s >> 10;
            my_p[j] = (unsigned)d | (gbit << 17) | (((unsigned)s & 1023u) << 18);
            my_v[j] = v;
            my_rank[j] = atomicAdd(&cnt[my_b[j]], 1);
        }
    }
    __syncthreads();

    // serial exclusive scan over 98 buckets (cheap, once per 4096 edges)
    if (t == 0) {
        int run = 0;
        for (int i = 0; i < NSB; ++i) { loff[i] = run; run += cnt[i]; }
        loff[NSB] = run;
    }
    __syncthreads();

    if (t < NSB) {
        int cc = cnt[t];
        gbase[t] = cc ? atomicAdd(&scur[t * 16], cc) : 0;   // padded counters: no line sharing
    }
    __syncthreads();

#pragma unroll
    for (int j = 0; j < 4; ++j) {
        if (my_ok[j]) {
            int lp = loff[my_b[j]] + my_rank[j];
            pay[lp] = make_uint2(my_p[j], __float_as_uint(my_v[j]));
            dest8[lp] = (unsigned char)my_b[j];
        }
    }
    __syncthreads();

    int tot = loff[NSB];
    for (int i = t; i < tot; i += 1024) {
        int bk = dest8[i];
        int go = gbase[bk] + (i - loff[bk]);
        if (go < SCAP) sp[(size_t)bk * SREG + go] = pay[i];
        else {
            int op = atomicAdd(ovf_cnt, 1);
            if (op < OVFCAP) {
                unsigned px = pay[i].x;
                ovf[3 * op] = (unsigned)(bk << 10) | ((px >> 18) & 1023u);
                ovf[3 * op + 1] = px;
                ovf[3 * op + 2] = pay[i].y;
            }
        }
    }
}

// Stage 2: one block per super.  Processes the slice in 13 chunks DESCENDING,
// scattering each chunk into 16 fine-bucket segments laid chunk-major at
// j*CREG (>= j*CHUNK -> never overwrites unread input: in-place).  All writes
// come from ONE CU -> lines accumulate in its L2, ~1x amplification.
__global__ __launch_bounds__(1024, 2) void partition2(
    const int* __restrict__ scur, uint2* __restrict__ pay,
    unsigned short* __restrict__ scnt,
    int* __restrict__ ovf_cnt, unsigned* __restrict__ ovf) {
    __shared__ int cntb[16][16];   // [wave][fine]
    __shared__ int woff[16][16];

    const int t = threadIdx.x;
    const int w = t >> 6;
    const int sbk = blockIdx.x;
    int m = scur[sbk * 16];
    if (m > SCAP) m = SCAP;
    uint2* base = pay + (size_t)sbk * SREG;

    uint2 pc[4]; int okc[4];
    {
        int lo = (NCH2 - 1) * CHUNK;
        int sz = m - lo; if (sz > CHUNK) sz = CHUNK;
#pragma unroll
        for (int k = 0; k < 4; ++k) {
            int i = t + k * 1024;
            okc[k] = (i < sz);
            pc[k] = okc[k] ? base[lo + i] : make_uint2(0u, 0u);
        }
    }
    for (int j = NCH2 - 1; j >= 0; --j) {
        uint2 pn[4]; int okn[4];
#pragma unroll
        for (int k = 0; k < 4; ++k) { pn[k] = make_uint2(0u, 0u); okn[k] = 0; }
        if (j > 0) {
            int lo2 = (j - 1) * CHUNK;
            int sz2 = m - lo2; if (sz2 > CHUNK) sz2 = CHUNK;
#pragma unroll
            for (int k = 0; k < 4; ++k) {
                int i = t + k * 1024;
                okn[k] = (i < sz2);
                if (okn[k]) pn[k] = base[lo2 + i];
            }
        }
        if (t < 256) cntb[t >> 4][t & 15] = 0;
        __syncthreads();
        int rk[4], fn[4];
#pragma unroll
        for (int k = 0; k < 4; ++k) {
            fn[k] = 0; rk[k] = 0;
            if (okc[k]) {
                fn[k] = (pc[k].x >> 24) & 15;
                rk[k] = atomicAdd(&cntb[w][fn[k]], 1);
            }
        }
        __syncthreads();
        if (t < 16) {
            int run = 0;
#pragma unroll
            for (int ww = 0; ww < 16; ++ww) { woff[ww][t] = run; run += cntb[ww][t]; }
            scnt[(sbk * NCH2 + j) * 16 + t] = (unsigned short)(run < SEGW ? run : SEGW);
        }
        __syncthreads();
        uint2* cbase = base + (size_t)j * CREG;
#pragma unroll
        for (int k = 0; k < 4; ++k) {
            if (okc[k]) {
                int pos = woff[w][fn[k]] + rk[k];
                if (pos < SEGW) cbase[fn[k] * SEGW + pos] = pc[k];
                else {
                    int op = atomicAdd(ovf_cnt, 1);
                    if (op < OVFCAP) {
                        unsigned px = pc[k].x;
                        ovf[3 * op] = (unsigned)(sbk << 10) | ((px >> 18) & 1023u);
                        ovf[3 * op + 1] = px;
                        ovf[3 * op + 2] = pc[k].y;
                    }
                }
            }
        }
#pragma unroll
        for (int k = 0; k < 4; ++k) { pc[k] = pn[k]; okc[k] = okn[k]; }
    }
}

// Gather: one block per 64-row fine bucket (98*16 = 1568).  R1 structure:
// register-staged single pass, 64-wide scan, spay place, 2x5-lane accumulate.
// Pass-1 iterates the 13 segments via a small prefix table.
__global__ __launch_bounds__(640, 7) void bucket_gather(
    const unsigned short* __restrict__ scnt, const uint2* __restrict__ pay,
    const unsigned short* __restrict__ g, float* __restrict__ out) {
    __shared__ unsigned spay[NCH2 * SEGW];   // 3744
    __shared__ int cnt[64];
    __shared__ int sb[64];
    __shared__ int rs[65];
    __shared__ int sps[NCH2 + 1];
    __shared__ float4 red4[64][10];

    const int t = threadIdx.x;
    const int b = blockIdx.x;          // fine id 0..1567
    const int sbk = b >> 4;
    const int f = b & 15;

    if (t < 64) cnt[t] = 0;
    if (t < NCH2) sps[t + 1] = (int)scnt[(sbk * NCH2 + t) * 16 + f];
    __syncthreads();
    if (t == 0) {
        sps[0] = 0;
        int run = 0;
#pragma unroll
        for (int j = 0; j < NCH2; ++j) { run += sps[j + 1]; sps[j + 1] = run; }
    }
    __syncthreads();
    const int n = sps[NCH2];

    const uint2* pb = pay + (size_t)sbk * SREG + f * SEGW;

    // pass 1: load payload into registers (static idx), count rows
    uint2 pe[6]; int rk[6];
#pragma unroll
    for (int jj = 0; jj < 6; ++jj) {
        int i = t + jj * 640;
        if (i < n) {
            int j = 0;
#pragma unroll
            for (int q = 1; q < NCH2; ++q) j += (i >= sps[q]);
            int off = i - sps[j];
            uint2 p = pb[(size_t)j * CREG + off];
            pe[jj] = p;
            rk[jj] = atomicAdd(&cnt[(p.x >> 18) & 63u], 1);
        }
    }
    __syncthreads();

    // 64-wide exclusive scan
    if (t < 64) sb[t] = cnt[t];
    __syncthreads();
    for (int off = 1; off < 64; off <<= 1) {
        int v = 0;
        if (t < 64 && t >= off) v = sb[t - off];
        __syncthreads();
        if (t < 64) sb[t] += v;
        __syncthreads();
    }
    if (t < 64) rs[t] = sb[t] - cnt[t];
    if (t == 63) rs[64] = sb[63];
    __syncthreads();

    // pass 2 (registers only): place into spay, quantize value to 14 bits
#pragma unroll
    for (int jj = 0; jj < 6; ++jj) {
        int i = t + jj * 640;
        if (i < n) {
            uint2 p = pe[jj];
            int pos = rs[(p.x >> 18) & 63u] + rk[jj];
            unsigned q = (unsigned)(__uint_as_float(p.y) * 16383.f + 0.5f);
            spay[pos] = (p.x & 0x3FFFFu) | (q << 18);
        }
    }
    __syncthreads();

    // accumulate: row le, 10 lanes = 2 groups x 5 lanes (8 cols each)
    const int le = t / 10;
    const int sub = t - le * 10;
    const int grp = (sub >= 5) ? 1 : 0;
    const int q8 = (sub - grp * 5) * 8;
    const float VS = 1.0f / 16383.0f;

    float4 a0 = make_float4(0.f, 0.f, 0.f, 0.f);
    float4 a1 = a0, b0 = a0, b1 = a0;
    const int estart = rs[le];
    const int eend = rs[le + 1];
    int e = estart + grp;
    for (; e + 6 < eend; e += 8) {
        unsigned p0 = spay[e], p1 = spay[e + 2], p2 = spay[e + 4], p3 = spay[e + 6];
        uint4 u0 = *(const uint4*)(g + (p0 & 0x3FFFFu) * 40u + q8);
        uint4 u1 = *(const uint4*)(g + (p1 & 0x3FFFFu) * 40u + q8);
        uint4 u2 = *(const uint4*)(g + (p2 & 0x3FFFFu) * 40u + q8);
        uint4 u3 = *(const uint4*)(g + (p3 & 0x3FFFFu) * 40u + q8);
        fma8(a0, a1, u0, (float)(p0 >> 18) * VS);
        fma8(b0, b1, u1, (float)(p1 >> 18) * VS);
        fma8(a0, a1, u2, (float)(p2 >> 18) * VS);
        fma8(b0, b1, u3, (float)(p3 >> 18) * VS);
    }
    for (; e < eend; e += 2) {
        unsigned p = spay[e];
        uint4 u = *(const uint4*)(g + (p & 0x3FFFFu) * 40u + q8);
        fma8(a0, a1, u, (float)(p >> 18) * VS);
    }
    a0.x += b0.x; a0.y += b0.y; a0.z += b0.z; a0.w += b0.w;
    a1.x += b1.x; a1.y += b1.y; a1.z += b1.z; a1.w += b1.w;

    // combine the two groups via LDS, then one RMW to out
    const int c2 = (q8 >> 2);  // 0,2,4,6,8
    __syncthreads();
    if (grp == 1) { red4[le][c2] = a0; red4[le][c2 + 1] = a1; }
    __syncthreads();
    if (grp == 0) {
        float4 r0 = red4[le][c2];
        float4 r1 = red4[le][c2 + 1];
        int gr = b * 64 + le;
        if (gr < Nn && eend > estart) {
            float* po = out + gr * 40 + q8;
            float4 o0 = *(const float4*)po;
            o0.x += a0.x + r0.x; o0.y += a0.y + r0.y;
            o0.z += a0.z + r0.z; o0.w += a0.w + r0.w;
            *(float4*)po = o0;
            float4 o1 = *(const float4*)(po + 4);
            o1.x += a1.x + r1.x; o1.y += a1.y + r1.y;
            o1.z += a1.z + r1.z; o1.w += a1.w + r1.w;
            *(float4*)(po + 4) = o1;
        }
    }
}

// Slow-path for rare overflow (super slice or segment spill).
__global__ __launch_bounds__(256) void ovf_scatter(
    const int* __restrict__ ovf_cnt, const unsigned* __restrict__ ovf,
    const unsigned short* __restrict__ g, float* __restrict__ out) {
    int n = *ovf_cnt;
    n = (n < OVFCAP) ? n : OVFCAP;
    int total = n * 40;
    for (int i = blockIdx.x * 256 + threadIdx.x; i < total; i += 2048) {
        int idx = i / 40, c = i % 40;
        unsigned s = ovf[3 * idx];
        unsigned p = ovf[3 * idx + 1];
        float v = __uint_as_float(ovf[3 * idx + 2]);
        unsigned rid = p & 0x3FFFFu;           // d | gbit<<17 — direct row id
        float gf = bf2f(g[rid * 40u + c]);
        unsafeAtomicAdd(out + s * 40 + c, v * gf);
    }
}

extern "C" void kernel_launch(void* const* d_in, const int* in_sizes, int n_in,
                              void* d_out, int out_size, void* d_ws, size_t ws_size,
                              hipStream_t stream) {
    const float* x        = (const float*)d_in[0];
    const int*   adj_src  = (const int*)d_in[2];
    const int*   adj_dst  = (const int*)d_in[3];
    const float* adj_val  = (const float*)d_in[4];
    const int*   adj2_src = (const int*)d_in[5];
    const int*   adj2_dst = (const int*)d_in[6];
    const float* adj2_val = (const float*)d_in[7];
    const float* fc1_w    = (const float*)d_in[8];
    const float* fc_out_w = (const float*)d_in[9];
    const float* fc_out_b = (const float*)d_in[10];
    float* out = (float*)d_out;

    char* ws = (char*)d_ws;
    unsigned short* Mb      = (unsigned short*)(ws + MP_OFF);
    unsigned short* g       = (unsigned short*)(ws + G_OFF);
    int*            scur    = (int*)(ws + SCUR_OFF);
    int*            ovf_cnt = (int*)(ws + OVFC_OFF);
    unsigned*       ovf     = (unsigned*)(ws + OVFL_OFF);
    unsigned short* scnt    = (unsigned short*)(ws + SCNT_OFF);
    uint2*          payload = (uint2*)(ws + PAY_OFF);

    const int E1 = in_sizes[2];
    const int E2 = in_sizes[5];
    const int Etot = E1 + E2;

    make_M<<<128, 256, 0, stream>>>(fc1_w, fc_out_w, Mb);
    gemm_mfma<<<(Nn + 127) / 128, 512, 0, stream>>>(x, Mb, fc_out_b, out, g);

    hipMemsetAsync(scur, 0, (OVFC_OFF - SCUR_OFF) + 16, stream);  // scur + ovf_cnt
    partition1<<<(Etot + CHUNK - 1) / CHUNK, 1024, 0, stream>>>(
        adj_src, adj_dst, adj_val, E1, adj2_src, adj2_dst, adj2_val, E2,
        scur, payload, ovf_cnt, ovf);
    partition2<<<NSB, 1024, 0, stream>>>(scur, payload, scnt, ovf_cnt, ovf);
    bucket_gather<<<NSB * 16, 640, 0, stream>>>(scnt, payload, g, out);
    ovf_scatter<<<8, 256, 0, stream>>>(ovf_cnt, ovf, g, out);
}

// Round 5
// 414.154 us; speedup vs baseline: 3.6841x; 1.3024x over previous
//
#include <hip/hip_runtime.h>

#define Nn 100000
#define INC 256
#define GEL 5242880u               // element offset of g2 = 131072*40 (18-bit rid addressing)
#define NSB 98                     // super-buckets: s>>10 (1024 rows each)
#define SCAP 51456                 // super slice capacity (mean 49152, +10.5 sigma)
#define NCH2 13                    // stage-2 chunks per super
#define SEGW 288                   // per-(chunk,fine) segment capacity (lambda=256, +2 sigma)
#define CREG 4608                  // 16*SEGW — per-chunk output region (>= CHUNK: in-place safe)
#define SREG 59904                 // 13*CREG — uint2 region per super (>= SCAP)
#define CHUNK 4096
#define OVFCAP 32768
#define BSTRIDE 264                // LDS stride (bf16) for M tile

// ---- workspace layout (bytes), total 68,442,384 (65.3 MB, proven in R4) ----
#define MP_OFF   0                 // bf16 M: 128*256*2 = 65536
#define G_OFF    65536             // bf16 g[2][131072][40] = 20,971,520
#define SCUR_OFF 21037056          // 98 counters padded to 64 B each = 6400
#define OVFC_OFF 21043456          // 1 int (16 B)
#define OVFL_OFF 21043472          // OVFCAP*12 = 393,216
#define SCNT_OFF 21436688          // 98*13*16 ushort = 40,768 (pad 40,960)
#define PAY_OFF  21477648          // 98*SREG*8 = 46,964,736

typedef __attribute__((ext_vector_type(8))) short bf16x8;
typedef __attribute__((ext_vector_type(4))) float f32x4;

__device__ __forceinline__ unsigned short f2bf(float f) {
    unsigned b = __float_as_uint(f);
    b += 0x7FFFu + ((b >> 16) & 1u);     // RNE
    return (unsigned short)(b >> 16);
}
__device__ __forceinline__ float bf2f(unsigned short u) {
    return __uint_as_float(((unsigned)u) << 16);
}

// 8 bf16 (packed in uint4) FMA into two float4 accumulators.
__device__ __forceinline__ void fma8(float4& a0, float4& a1, uint4 u, float v) {
    a0.x = fmaf(v, __uint_as_float(u.x << 16), a0.x);
    a0.y = fmaf(v, __uint_as_float(u.x & 0xFFFF0000u), a0.y);
    a0.z = fmaf(v, __uint_as_float(u.y << 16), a0.z);
    a0.w = fmaf(v, __uint_as_float(u.y & 0xFFFF0000u), a0.w);
    a1.x = fmaf(v, __uint_as_float(u.z << 16), a1.x);
    a1.y = fmaf(v, __uint_as_float(u.z & 0xFFFF0000u), a1.y);
    a1.z = fmaf(v, __uint_as_float(u.w << 16), a1.z);
    a1.w = fmaf(v, __uint_as_float(u.w & 0xFFFF0000u), a1.w);
}

// Mb[128][256] bf16
__global__ void make_M(const float* __restrict__ fc1_w,
                       const float* __restrict__ fc_out_w,
                       unsigned short* __restrict__ Mb) {
    int j = blockIdx.x;   // 0..127
    int k = threadIdx.x;  // 0..255
    float acc = 0.f;
    if (j < 120) {
        int i = j / 40, o = j - i * 40;
        const float* wrow = fc_out_w + o * 192 + i * 64;
#pragma unroll 8
        for (int t = 0; t < 64; ++t)
            acc = fmaf(wrow[t], fc1_w[t * 256 + k], acc);
    }
    Mb[j * 256 + k] = (j < 120) ? f2bf(acc) : (unsigned short)0;
}

// MFMA bf16 GEMM: block = 128 rows x 120 cols, 8 waves (16 rows each).
__global__ __launch_bounds__(512, 4) void gemm_mfma(
    const float* __restrict__ x, const unsigned short* __restrict__ Mb,
    const float* __restrict__ bias, float* __restrict__ out,
    unsigned short* __restrict__ g) {
    __shared__ unsigned short mlds[120 * BSTRIDE];
    const int tid = threadIdx.x;
    const int w = tid >> 6;
    const int l = tid & 63;
    const int lane15 = l & 15;
    const int quad = l >> 4;

    for (int i = tid; i < 3840; i += 512) {
        int r = i >> 5;
        int k8 = (i & 31) * 8;
        uint4 v = *(const uint4*)(Mb + r * 256 + k8);
        *(uint4*)(mlds + r * BSTRIDE + k8) = v;
    }
    __syncthreads();

    const int arow = blockIdx.x * 128 + w * 16 + lane15;
    const bool rok = arow < Nn;
    const float* xp = x + (size_t)arow * INC + quad * 8;

    f32x4 acc[8];
#pragma unroll
    for (int c = 0; c < 8; ++c) acc[c] = (f32x4){0.f, 0.f, 0.f, 0.f};

    float4 pa[3], pb_[3];
#pragma unroll
    for (int p = 0; p < 2; ++p) {
        pa[p] = make_float4(0, 0, 0, 0); pb_[p] = make_float4(0, 0, 0, 0);
        if (rok) { pa[p] = *(const float4*)(xp + p * 32); pb_[p] = *(const float4*)(xp + p * 32 + 4); }
    }

#pragma unroll
    for (int kt = 0; kt < 8; ++kt) {
        const int nb = (kt + 2) % 3;
        if (kt + 2 < 8) {
            pa[nb] = make_float4(0, 0, 0, 0); pb_[nb] = make_float4(0, 0, 0, 0);
            if (rok) {
                pa[nb] = *(const float4*)(xp + (kt + 2) * 32);
                pb_[nb] = *(const float4*)(xp + (kt + 2) * 32 + 4);
            }
        }
        const int cu = kt % 3;
        bf16x8 af;
        af[0] = (short)f2bf(pa[cu].x); af[1] = (short)f2bf(pa[cu].y);
        af[2] = (short)f2bf(pa[cu].z); af[3] = (short)f2bf(pa[cu].w);
        af[4] = (short)f2bf(pb_[cu].x); af[5] = (short)f2bf(pb_[cu].y);
        af[6] = (short)f2bf(pb_[cu].z); af[7] = (short)f2bf(pb_[cu].w);
        const unsigned short* bbase = mlds + kt * 32 + quad * 8 + lane15 * BSTRIDE;
#pragma unroll
        for (int ct = 0; ct < 8; ++ct) {
            if (ct * 16 >= 120) break;
            bf16x8 bf = *(const bf16x8*)(bbase + ct * 16 * BSTRIDE);
            acc[ct] = __builtin_amdgcn_mfma_f32_16x16x32_bf16(af, bf, acc[ct], 0, 0, 0);
        }
    }

#pragma unroll
    for (int ct = 0; ct < 8; ++ct) {
        int col = ct * 16 + lane15;
        if (col >= 120) continue;
        int ib = col / 40;
        int cc = col - ib * 40;
        float badd = (ib == 0) ? bias[cc] : 0.f;
#pragma unroll
        for (int reg = 0; reg < 4; ++reg) {
            int gr = blockIdx.x * 128 + w * 16 + quad * 4 + reg;
            if (gr >= Nn) continue;
            float v = acc[ct][reg] + badd;
            if (ib == 0) out[gr * 40 + cc] = v;
            else g[(unsigned)(ib - 1) * GEL + (unsigned)gr * 40u + cc] = f2bf(v);
        }
    }
}

// Stage 1: chunk-local LDS sort into 98 SUPER-buckets (s>>10).  Runs are
// ~42 edges (334 B) -> coalesced, ~1.1x line amplification.
// Entry: {d | gbit<<17 | (s&1023)<<18, v_f32}.
__global__ __launch_bounds__(1024, 8) void partition1(
    const int* __restrict__ s1, const int* __restrict__ d1, const float* __restrict__ v1, int E1,
    const int* __restrict__ s2, const int* __restrict__ d2, const float* __restrict__ v2, int E2,
    int* __restrict__ scur, uint2* __restrict__ sp,
    int* __restrict__ ovf_cnt, unsigned* __restrict__ ovf) {
    __shared__ int cnt[NSB];
    __shared__ int loff[NSB + 1];
    __shared__ int gbase[NSB];
    __shared__ uint2 pay[CHUNK];
    __shared__ unsigned char dest8[CHUNK];

    const int t = threadIdx.x;
    const int Etot = E1 + E2;
    const int e0 = blockIdx.x * CHUNK;

    for (int i = t; i < NSB; i += 1024) cnt[i] = 0;
    __syncthreads();

    int my_b[4]; int my_rank[4]; unsigned my_p[4]; float my_v[4]; bool my_ok[4];
#pragma unroll
    for (int j = 0; j < 4; ++j) {
        int e = e0 + j * 1024 + t;
        my_ok[j] = (e < Etot);
        if (my_ok[j]) {
            int s, d; float v; unsigned gbit;
            if (e < E1) { s = s1[e]; d = d1[e]; v = v1[e]; gbit = 0u; }
            else { int e2 = e - E1; s = s2[e2]; d = d2[e2]; v = v2[e2]; gbit = 1u; }
            my_b[j] = s >> 10;
            my_p[j] = (unsigned)d | (gbit << 17) | (((unsigned)s & 1023u) << 18);
            my_v[j] = v;
            my_rank[j] = atomicAdd(&cnt[my_b[j]], 1);
        }
    }
    __syncthreads();

    // serial exclusive scan over 98 buckets (cheap, once per 4096 edges)
    if (t == 0) {
        int run = 0;
        for (int i = 0; i < NSB; ++i) { loff[i] = run; run += cnt[i]; }
        loff[NSB] = run;
    }
    __syncthreads();

    if (t < NSB) {
        int cc = cnt[t];
        gbase[t] = cc ? atomicAdd(&scur[t * 16], cc) : 0;   // padded counters: no line sharing
    }
    __syncthreads();

#pragma unroll
    for (int j = 0; j < 4; ++j) {
        if (my_ok[j]) {
            int lp = loff[my_b[j]] + my_rank[j];
            pay[lp] = make_uint2(my_p[j], __float_as_uint(my_v[j]));
            dest8[lp] = (unsigned char)my_b[j];
        }
    }
    __syncthreads();

    int tot = loff[NSB];
    for (int i = t; i < tot; i += 1024) {
        int bk = dest8[i];
        int go = gbase[bk] + (i - loff[bk]);
        if (go < SCAP) sp[(size_t)bk * SREG + go] = pay[i];
        else {
            int op = atomicAdd(ovf_cnt, 1);
            if (op < OVFCAP) {
                unsigned px = pay[i].x;
                ovf[3 * op] = (unsigned)(bk << 10) | ((px >> 18) & 1023u);
                ovf[3 * op + 1] = px;
                ovf[3 * op + 2] = pay[i].y;
            }
        }
    }
}

// Stage 2: one block per super.  Processes the slice in 13 chunks DESCENDING,
// scattering each chunk into 16 fine-bucket segments laid chunk-major at
// j*CREG (>= j*CHUNK -> never overwrites unread input: in-place).  All writes
// come from ONE CU -> lines accumulate in its L2, ~1x amplification.
__global__ __launch_bounds__(1024, 2) void partition2(
    const int* __restrict__ scur, uint2* __restrict__ pay,
    unsigned short* __restrict__ scnt,
    int* __restrict__ ovf_cnt, unsigned* __restrict__ ovf) {
    __shared__ int cntb[16][16];   // [wave][fine]
    __shared__ int woff[16][16];

    const int t = threadIdx.x;
    const int w = t >> 6;
    const int sbk = blockIdx.x;
    int m = scur[sbk * 16];
    if (m > SCAP) m = SCAP;
    uint2* base = pay + (size_t)sbk * SREG;

    uint2 pc[4]; int okc[4];
    {
        int lo = (NCH2 - 1) * CHUNK;
        int sz = m - lo; if (sz > CHUNK) sz = CHUNK;
#pragma unroll
        for (int k = 0; k < 4; ++k) {
            int i = t + k * 1024;
            okc[k] = (i < sz);
            pc[k] = okc[k] ? base[lo + i] : make_uint2(0u, 0u);
        }
    }
    for (int j = NCH2 - 1; j >= 0; --j) {
        uint2 pn[4]; int okn[4];
#pragma unroll
        for (int k = 0; k < 4; ++k) { pn[k] = make_uint2(0u, 0u); okn[k] = 0; }
        if (j > 0) {
            int lo2 = (j - 1) * CHUNK;
            int sz2 = m - lo2; if (sz2 > CHUNK) sz2 = CHUNK;
#pragma unroll
            for (int k = 0; k < 4; ++k) {
                int i = t + k * 1024;
                okn[k] = (i < sz2);
                if (okn[k]) pn[k] = base[lo2 + i];
            }
        }
        if (t < 256) cntb[t >> 4][t & 15] = 0;
        __syncthreads();
        int rk[4], fn[4];
#pragma unroll
        for (int k = 0; k < 4; ++k) {
            fn[k] = 0; rk[k] = 0;
            if (okc[k]) {
                fn[k] = (pc[k].x >> 24) & 15;
                rk[k] = atomicAdd(&cntb[w][fn[k]], 1);
            }
        }
        __syncthreads();
        if (t < 16) {
            int run = 0;
#pragma unroll
            for (int ww = 0; ww < 16; ++ww) { woff[ww][t] = run; run += cntb[ww][t]; }
            scnt[(sbk * NCH2 + j) * 16 + t] = (unsigned short)(run < SEGW ? run : SEGW);
        }
        __syncthreads();
        uint2* cbase = base + (size_t)j * CREG;
#pragma unroll
        for (int k = 0; k < 4; ++k) {
            if (okc[k]) {
                int pos = woff[w][fn[k]] + rk[k];
                if (pos < SEGW) cbase[fn[k] * SEGW + pos] = pc[k];
                else {
                    int op = atomicAdd(ovf_cnt, 1);
                    if (op < OVFCAP) {
                        unsigned px = pc[k].x;
                        ovf[3 * op] = (unsigned)(sbk << 10) | ((px >> 18) & 1023u);
                        ovf[3 * op + 1] = px;
                        ovf[3 * op + 2] = pc[k].y;
                    }
                }
            }
        }
#pragma unroll
        for (int k = 0; k < 4; ++k) { pc[k] = pn[k]; okc[k] = okn[k]; }
    }
}

// Gather: one block per 64-row fine bucket (98*16 = 1568).  Register-staged
// single pass, 64-wide scan, spay place, 2x5-lane accumulate.
__global__ __launch_bounds__(640, 7) void bucket_gather(
    const unsigned short* __restrict__ scnt, const uint2* __restrict__ pay,
    const unsigned short* __restrict__ g, float* __restrict__ out) {
    __shared__ unsigned spay[NCH2 * SEGW];   // 3744
    __shared__ int cnt[64];
    __shared__ int sb[64];
    __shared__ int rs[65];
    __shared__ int sps[NCH2 + 1];
    __shared__ float4 red4[64][10];

    const int t = threadIdx.x;
    const int b = blockIdx.x;          // fine id 0..1567
    const int sbk = b >> 4;
    const int f = b & 15;

    if (t < 64) cnt[t] = 0;
    if (t < NCH2) sps[t + 1] = (int)scnt[(sbk * NCH2 + t) * 16 + f];
    __syncthreads();
    if (t == 0) {
        sps[0] = 0;
        int run = 0;
#pragma unroll
        for (int j = 0; j < NCH2; ++j) { run += sps[j + 1]; sps[j + 1] = run; }
    }
    __syncthreads();
    const int n = sps[NCH2];

    const uint2* pb = pay + (size_t)sbk * SREG + f * SEGW;

    // pass 1: load payload into registers (static idx), count rows
    uint2 pe[6]; int rk[6];
#pragma unroll
    for (int jj = 0; jj < 6; ++jj) {
        int i = t + jj * 640;
        if (i < n) {
            int j = 0;
#pragma unroll
            for (int q = 1; q < NCH2; ++q) j += (i >= sps[q]);
            int off = i - sps[j];
            uint2 p = pb[(size_t)j * CREG + off];
            pe[jj] = p;
            rk[jj] = atomicAdd(&cnt[(p.x >> 18) & 63u], 1);
        }
    }
    __syncthreads();

    // 64-wide exclusive scan
    if (t < 64) sb[t] = cnt[t];
    __syncthreads();
    for (int off = 1; off < 64; off <<= 1) {
        int v = 0;
        if (t < 64 && t >= off) v = sb[t - off];
        __syncthreads();
        if (t < 64) sb[t] += v;
        __syncthreads();
    }
    if (t < 64) rs[t] = sb[t] - cnt[t];
    if (t == 63) rs[64] = sb[63];
    __syncthreads();

    // pass 2 (registers only): place into spay, quantize value to 14 bits
#pragma unroll
    for (int jj = 0; jj < 6; ++jj) {
        int i = t + jj * 640;
        if (i < n) {
            uint2 p = pe[jj];
            int pos = rs[(p.x >> 18) & 63u] + rk[jj];
            unsigned q = (unsigned)(__uint_as_float(p.y) * 16383.f + 0.5f);
            spay[pos] = (p.x & 0x3FFFFu) | (q << 18);
        }
    }
    __syncthreads();

    // accumulate: row le, 10 lanes = 2 groups x 5 lanes (8 cols each)
    const int le = t / 10;
    const int sub = t - le * 10;
    const int grp = (sub >= 5) ? 1 : 0;
    const int q8 = (sub - grp * 5) * 8;
    const float VS = 1.0f / 16383.0f;

    float4 a0 = make_float4(0.f, 0.f, 0.f, 0.f);
    float4 a1 = a0, b0 = a0, b1 = a0;
    const int estart = rs[le];
    const int eend = rs[le + 1];
    int e = estart + grp;
    for (; e + 6 < eend; e += 8) {
        unsigned p0 = spay[e], p1 = spay[e + 2], p2 = spay[e + 4], p3 = spay[e + 6];
        uint4 u0 = *(const uint4*)(g + (p0 & 0x3FFFFu) * 40u + q8);
        uint4 u1 = *(const uint4*)(g + (p1 & 0x3FFFFu) * 40u + q8);
        uint4 u2 = *(const uint4*)(g + (p2 & 0x3FFFFu) * 40u + q8);
        uint4 u3 = *(const uint4*)(g + (p3 & 0x3FFFFu) * 40u + q8);
        fma8(a0, a1, u0, (float)(p0 >> 18) * VS);
        fma8(b0, b1, u1, (float)(p1 >> 18) * VS);
        fma8(a0, a1, u2, (float)(p2 >> 18) * VS);
        fma8(b0, b1, u3, (float)(p3 >> 18) * VS);
    }
    for (; e < eend; e += 2) {
        unsigned p = spay[e];
        uint4 u = *(const uint4*)(g + (p & 0x3FFFFu) * 40u + q8);
        fma8(a0, a1, u, (float)(p >> 18) * VS);
    }
    a0.x += b0.x; a0.y += b0.y; a0.z += b0.z; a0.w += b0.w;
    a1.x += b1.x; a1.y += b1.y; a1.z += b1.z; a1.w += b1.w;

    // combine the two groups via LDS, then one RMW to out
    const int c2 = (q8 >> 2);  // 0,2,4,6,8
    __syncthreads();
    if (grp == 1) { red4[le][c2] = a0; red4[le][c2 + 1] = a1; }
    __syncthreads();
    if (grp == 0) {
        float4 r0 = red4[le][c2];
        float4 r1 = red4[le][c2 + 1];
        int gr = b * 64 + le;
        if (gr < Nn && eend > estart) {
            float* po = out + gr * 40 + q8;
            float4 o0 = *(const float4*)po;
            o0.x += a0.x + r0.x; o0.y += a0.y + r0.y;
            o0.z += a0.z + r0.z; o0.w += a0.w + r0.w;
            *(float4*)po = o0;
            float4 o1 = *(const float4*)(po + 4);
            o1.x += a1.x + r1.x; o1.y += a1.y + r1.y;
            o1.z += a1.z + r1.z; o1.w += a1.w + r1.w;
            *(float4*)(po + 4) = o1;
        }
    }
}

// Slow-path for rare overflow (super slice or segment spill).  Properly
// parallel grid (R4 post-mortem: the 8-block launch made ~372K scattered
// work items a 133 us latency chain on 8 CUs).
__global__ __launch_bounds__(256) void ovf_scatter(
    const int* __restrict__ ovf_cnt, const unsigned* __restrict__ ovf,
    const unsigned short* __restrict__ g, float* __restrict__ out) {
    int n = *ovf_cnt;
    n = (n < OVFCAP) ? n : OVFCAP;
    int total = n * 40;
    const int stride = gridDim.x * blockDim.x;
    for (int i = blockIdx.x * blockDim.x + threadIdx.x; i < total; i += stride) {
        int idx = i / 40, c = i % 40;
        unsigned s = ovf[3 * idx];
        unsigned p = ovf[3 * idx + 1];
        float v = __uint_as_float(ovf[3 * idx + 2]);
        unsigned rid = p & 0x3FFFFu;           // d | gbit<<17 — direct row id
        float gf = bf2f(g[rid * 40u + c]);
        unsafeAtomicAdd(out + s * 40 + c, v * gf);
    }
}

extern "C" void kernel_launch(void* const* d_in, const int* in_sizes, int n_in,
                              void* d_out, int out_size, void* d_ws, size_t ws_size,
                              hipStream_t stream) {
    const float* x        = (const float*)d_in[0];
    const int*   adj_src  = (const int*)d_in[2];
    const int*   adj_dst  = (const int*)d_in[3];
    const float* adj_val  = (const float*)d_in[4];
    const int*   adj2_src = (const int*)d_in[5];
    const int*   adj2_dst = (const int*)d_in[6];
    const float* adj2_val = (const float*)d_in[7];
    const float* fc1_w    = (const float*)d_in[8];
    const float* fc_out_w = (const float*)d_in[9];
    const float* fc_out_b = (const float*)d_in[10];
    float* out = (float*)d_out;

    char* ws = (char*)d_ws;
    unsigned short* Mb      = (unsigned short*)(ws + MP_OFF);
    unsigned short* g       = (unsigned short*)(ws + G_OFF);
    int*            scur    = (int*)(ws + SCUR_OFF);
    int*            ovf_cnt = (int*)(ws + OVFC_OFF);
    unsigned*       ovf     = (unsigned*)(ws + OVFL_OFF);
    unsigned short* scnt    = (unsigned short*)(ws + SCNT_OFF);
    uint2*          payload = (uint2*)(ws + PAY_OFF);

    const int E1 = in_sizes[2];
    const int E2 = in_sizes[5];
    const int Etot = E1 + E2;

    make_M<<<128, 256, 0, stream>>>(fc1_w, fc_out_w, Mb);
    gemm_mfma<<<(Nn + 127) / 128, 512, 0, stream>>>(x, Mb, fc_out_b, out, g);

    hipMemsetAsync(scur, 0, (OVFC_OFF - SCUR_OFF) + 16, stream);  // scur + ovf_cnt
    partition1<<<(Etot + CHUNK - 1) / CHUNK, 1024, 0, stream>>>(
        adj_src, adj_dst, adj_val, E1, adj2_src, adj2_dst, adj2_val, E2,
        scur, payload, ovf_cnt, ovf);
    partition2<<<NSB, 1024, 0, stream>>>(scur, payload, scnt, ovf_cnt, ovf);
    bucket_gather<<<NSB * 16, 640, 0, stream>>>(scnt, payload, g, out);
    ovf_scatter<<<512, 256, 0, stream>>>(ovf_cnt, ovf, g, out);
}

// Round 6
// 399.511 us; speedup vs baseline: 3.8191x; 1.0367x over previous
//
#include <hip/hip_runtime.h>

#define Nn 100000
#define INC 256
#define NB 1563                    // buckets: src>>6, 64 rows each
#define CAP64 3744                 // edges per bucket (mean 3072, ~12 sigma)
#define CHUNK 4096                 // edges per partition block
#define OVFCAP 32768
#define BSTRIDE 264                // LDS stride (bf16) for M tile

// ---- workspace layout (bytes), total 68,251,664 (< proven 68,442,384) ----
// g split planes (R5 post-mortem: 80 B rows at pitch 80 always span TWO 64 B
// lines -> 9.6M random line-fetches; split planes cut it to ~4.8M):
//   plane A: cols 0..31, 64 B/row, line-aligned, idx rid*32
//   plane B: cols 32..39, 16 B/row, idx rid*8 (4.2 MB total -> L2-resident)
#define MP_OFF   0                 // bf16 M: 128*256*2 = 65536
#define GA_OFF   65536             // bf16 gA[262144][32] = 16,777,216
#define GB_OFF   16842752          // bf16 gB[262144][8]  =  4,194,304
#define GCUR_OFF 21037056          // NB ints = 6252 (pad 6400)
#define OVFC_OFF 21043456          // 1 int (16 B)
#define OVFL_OFF 21043472          // OVFCAP*12 = 393,216
#define PAY_OFF  21436688          // NB*CAP64*8 = 46,814,976

typedef __attribute__((ext_vector_type(8))) short bf16x8;
typedef __attribute__((ext_vector_type(4))) float f32x4;

__device__ __forceinline__ unsigned short f2bf(float f) {
    unsigned b = __float_as_uint(f);
    b += 0x7FFFu + ((b >> 16) & 1u);     // RNE
    return (unsigned short)(b >> 16);
}
__device__ __forceinline__ float bf2f(unsigned short u) {
    return __uint_as_float(((unsigned)u) << 16);
}

// 8 bf16 (packed in uint4) FMA into two float4 accumulators.
__device__ __forceinline__ void fma8(float4& a0, float4& a1, uint4 u, float v) {
    a0.x = fmaf(v, __uint_as_float(u.x << 16), a0.x);
    a0.y = fmaf(v, __uint_as_float(u.x & 0xFFFF0000u), a0.y);
    a0.z = fmaf(v, __uint_as_float(u.y << 16), a0.z);
    a0.w = fmaf(v, __uint_as_float(u.y & 0xFFFF0000u), a0.w);
    a1.x = fmaf(v, __uint_as_float(u.z << 16), a1.x);
    a1.y = fmaf(v, __uint_as_float(u.z & 0xFFFF0000u), a1.y);
    a1.z = fmaf(v, __uint_as_float(u.w << 16), a1.z);
    a1.w = fmaf(v, __uint_as_float(u.w & 0xFFFF0000u), a1.w);
}

// Mb[128][256] bf16
__global__ void make_M(const float* __restrict__ fc1_w,
                       const float* __restrict__ fc_out_w,
                       unsigned short* __restrict__ Mb) {
    int j = blockIdx.x;   // 0..127
    int k = threadIdx.x;  // 0..255
    float acc = 0.f;
    if (j < 120) {
        int i = j / 40, o = j - i * 40;
        const float* wrow = fc_out_w + o * 192 + i * 64;
#pragma unroll 8
        for (int t = 0; t < 64; ++t)
            acc = fmaf(wrow[t], fc1_w[t * 256 + k], acc);
    }
    Mb[j * 256 + k] = (j < 120) ? f2bf(acc) : (unsigned short)0;
}

// MFMA bf16 GEMM: block = 128 rows x 120 cols, 8 waves (16 rows each).
__global__ __launch_bounds__(512, 4) void gemm_mfma(
    const float* __restrict__ x, const unsigned short* __restrict__ Mb,
    const float* __restrict__ bias, float* __restrict__ out,
    unsigned short* __restrict__ gA, unsigned short* __restrict__ gB) {
    __shared__ unsigned short mlds[120 * BSTRIDE];
    const int tid = threadIdx.x;
    const int w = tid >> 6;
    const int l = tid & 63;
    const int lane15 = l & 15;
    const int quad = l >> 4;

    for (int i = tid; i < 3840; i += 512) {
        int r = i >> 5;
        int k8 = (i & 31) * 8;
        uint4 v = *(const uint4*)(Mb + r * 256 + k8);
        *(uint4*)(mlds + r * BSTRIDE + k8) = v;
    }
    __syncthreads();

    const int arow = blockIdx.x * 128 + w * 16 + lane15;
    const bool rok = arow < Nn;
    const float* xp = x + (size_t)arow * INC + quad * 8;

    f32x4 acc[8];
#pragma unroll
    for (int c = 0; c < 8; ++c) acc[c] = (f32x4){0.f, 0.f, 0.f, 0.f};

    float4 pa[3], pb_[3];
#pragma unroll
    for (int p = 0; p < 2; ++p) {
        pa[p] = make_float4(0, 0, 0, 0); pb_[p] = make_float4(0, 0, 0, 0);
        if (rok) { pa[p] = *(const float4*)(xp + p * 32); pb_[p] = *(const float4*)(xp + p * 32 + 4); }
    }

#pragma unroll
    for (int kt = 0; kt < 8; ++kt) {
        const int nb = (kt + 2) % 3;
        if (kt + 2 < 8) {
            pa[nb] = make_float4(0, 0, 0, 0); pb_[nb] = make_float4(0, 0, 0, 0);
            if (rok) {
                pa[nb] = *(const float4*)(xp + (kt + 2) * 32);
                pb_[nb] = *(const float4*)(xp + (kt + 2) * 32 + 4);
            }
        }
        const int cu = kt % 3;
        bf16x8 af;
        af[0] = (short)f2bf(pa[cu].x); af[1] = (short)f2bf(pa[cu].y);
        af[2] = (short)f2bf(pa[cu].z); af[3] = (short)f2bf(pa[cu].w);
        af[4] = (short)f2bf(pb_[cu].x); af[5] = (short)f2bf(pb_[cu].y);
        af[6] = (short)f2bf(pb_[cu].z); af[7] = (short)f2bf(pb_[cu].w);
        const unsigned short* bbase = mlds + kt * 32 + quad * 8 + lane15 * BSTRIDE;
#pragma unroll
        for (int ct = 0; ct < 8; ++ct) {
            if (ct * 16 >= 120) break;
            bf16x8 bf = *(const bf16x8*)(bbase + ct * 16 * BSTRIDE);
            acc[ct] = __builtin_amdgcn_mfma_f32_16x16x32_bf16(af, bf, acc[ct], 0, 0, 0);
        }
    }

#pragma unroll
    for (int ct = 0; ct < 8; ++ct) {
        int col = ct * 16 + lane15;
        if (col >= 120) continue;
        int ib = col / 40;
        int cc = col - ib * 40;
        float badd = (ib == 0) ? bias[cc] : 0.f;
#pragma unroll
        for (int reg = 0; reg < 4; ++reg) {
            int gr = blockIdx.x * 128 + w * 16 + quad * 4 + reg;
            if (gr >= Nn) continue;
            float v = acc[ct][reg] + badd;
            if (ib == 0) out[gr * 40 + cc] = v;
            else {
                unsigned rid = (unsigned)gr + ((unsigned)(ib - 1) << 17);
                if (cc < 32) gA[rid * 32u + cc] = f2bf(v);
                else         gB[rid * 8u + (cc - 32)] = f2bf(v);
            }
        }
    }
}

// Partition: chunk-local LDS sort into 64-row buckets (src>>6), coalesced
// per-bucket run writes (single-stage — R5 post-mortem: two-stage was a net
// ~27 us loss).  Entry: {d | gbit<<17 | (s&63)<<18, v_f32}.
__global__ __launch_bounds__(1024, 8) void partition(
    const int* __restrict__ s1, const int* __restrict__ d1, const float* __restrict__ v1, int E1,
    const int* __restrict__ s2, const int* __restrict__ d2, const float* __restrict__ v2, int E2,
    int* __restrict__ gcur, uint2* __restrict__ payload,
    int* __restrict__ ovf_cnt, unsigned* __restrict__ ovf) {
    __shared__ int cnt[NB];
    __shared__ int loff[NB + 1];
    __shared__ int gbase[NB];
    __shared__ int scanbuf[1024];
    __shared__ uint2 pay[CHUNK];
    __shared__ unsigned short dest16[CHUNK];

    const int t = threadIdx.x;
    const int Etot = E1 + E2;
    const int e0 = blockIdx.x * CHUNK;

    for (int i = t; i < NB; i += 1024) cnt[i] = 0;
    __syncthreads();

    int my_b[4]; int my_rank[4]; unsigned my_p[4]; float my_v[4]; bool my_ok[4];
#pragma unroll
    for (int j = 0; j < 4; ++j) {
        int e = e0 + j * 1024 + t;
        my_ok[j] = (e < Etot);
        if (my_ok[j]) {
            int s, d; float v; unsigned gbit;
            if (e < E1) { s = s1[e]; d = d1[e]; v = v1[e]; gbit = 0u; }
            else { int e2 = e - E1; s = s2[e2]; d = d2[e2]; v = v2[e2]; gbit = 1u; }
            my_b[j] = s >> 6;
            my_p[j] = (unsigned)d | (gbit << 17) | (((unsigned)s & 63u) << 18);
            my_v[j] = v;
            my_rank[j] = atomicAdd(&cnt[my_b[j]], 1);
        }
    }
    __syncthreads();

    // exclusive scan over NB (< 2048): pairwise, thread t owns slots 2t, 2t+1
    int c0 = (2 * t < NB) ? cnt[2 * t] : 0;
    int c1 = (2 * t + 1 < NB) ? cnt[2 * t + 1] : 0;
    scanbuf[t] = c0 + c1;
    __syncthreads();
    for (int off = 1; off < 1024; off <<= 1) {
        int v = (t >= off) ? scanbuf[t - off] : 0;
        __syncthreads();
        scanbuf[t] += v;
        __syncthreads();
    }
    int ex = scanbuf[t] - (c0 + c1);
    if (2 * t < NB)     loff[2 * t] = ex;
    if (2 * t + 1 < NB) loff[2 * t + 1] = ex + c0;
    if (t == 1023)      loff[NB] = scanbuf[1023];
    __syncthreads();

    for (int i = t; i < NB; i += 1024) {
        int cc = cnt[i];
        gbase[i] = cc ? atomicAdd(&gcur[i], cc) : 0;
    }
    __syncthreads();

#pragma unroll
    for (int j = 0; j < 4; ++j) {
        if (my_ok[j]) {
            int lp = loff[my_b[j]] + my_rank[j];
            pay[lp] = make_uint2(my_p[j], __float_as_uint(my_v[j]));
            dest16[lp] = (unsigned short)my_b[j];
        }
    }
    __syncthreads();

    int tot = loff[NB];
    for (int i = t; i < tot; i += 1024) {
        int b = dest16[i];
        int go = gbase[b] + (i - loff[b]);
        if (go < CAP64) payload[(size_t)b * CAP64 + go] = pay[i];
        else {
            int op = atomicAdd(ovf_cnt, 1);
            if (op < OVFCAP) {
                unsigned px = pay[i].x;
                ovf[3 * op] = ((unsigned)b << 6) | ((px >> 18) & 63u);
                ovf[3 * op + 1] = px;
                ovf[3 * op + 2] = pay[i].y;
            }
        }
    }
}

// Gather: one block per 64-row bucket.  Register-staged single pass, 64-wide
// scan, spay place, then 2 groups x 5 lanes per row: lanes q8<32 read ONE
// aligned 64 B line slice from plane A, lane q8==32 reads 16 B from the
// L2-resident plane B.
__global__ __launch_bounds__(640, 7) void bucket_gather(
    const int* __restrict__ gcur, const uint2* __restrict__ payload,
    const unsigned short* __restrict__ gA, const unsigned short* __restrict__ gB,
    float* __restrict__ out) {
    __shared__ unsigned spay[CAP64];
    __shared__ int cnt[64];
    __shared__ int sb[64];
    __shared__ int rs[65];
    __shared__ float4 red4[64][10];

    const int t = threadIdx.x;
    const int b = blockIdx.x;
    int n = gcur[b];
    n = (n < CAP64) ? n : CAP64;

    if (t < 64) cnt[t] = 0;
    __syncthreads();

    const uint2* pb = payload + (size_t)b * CAP64;

    // pass 1: load payload into registers (static idx), count rows
    uint2 pe[6]; int rk[6];
#pragma unroll
    for (int j = 0; j < 6; ++j) {
        int i = t + j * 640;
        if (i < n) {
            uint2 p = pb[i];
            pe[j] = p;
            rk[j] = atomicAdd(&cnt[(p.x >> 18) & 63u], 1);
        }
    }
    __syncthreads();

    // 64-wide exclusive scan
    if (t < 64) sb[t] = cnt[t];
    __syncthreads();
    for (int off = 1; off < 64; off <<= 1) {
        int v = 0;
        if (t < 64 && t >= off) v = sb[t - off];
        __syncthreads();
        if (t < 64) sb[t] += v;
        __syncthreads();
    }
    if (t < 64) rs[t] = sb[t] - cnt[t];
    if (t == 63) rs[64] = sb[63];
    __syncthreads();

    // pass 2 (registers only): place into spay, quantize value to 14 bits
#pragma unroll
    for (int j = 0; j < 6; ++j) {
        int i = t + j * 640;
        if (i < n) {
            uint2 p = pe[j];
            int pos = rs[(p.x >> 18) & 63u] + rk[j];
            unsigned q = (unsigned)(__uint_as_float(p.y) * 16383.f + 0.5f);
            spay[pos] = (p.x & 0x3FFFFu) | (q << 18);
        }
    }
    __syncthreads();

    // accumulate: row le, 10 lanes = 2 groups x 5 lanes (8 cols each)
    const int le = t / 10;
    const int sub = t - le * 10;
    const int grp = (sub >= 5) ? 1 : 0;
    const int q8 = (sub - grp * 5) * 8;
    const float VS = 1.0f / 16383.0f;

    // per-lane plane select: q8 in {0,8,16,24} -> plane A; q8==32 -> plane B
    const unsigned short* ub;
    unsigned scale;
    if (q8 < 32) { ub = gA + q8; scale = 32u; }
    else         { ub = gB;      scale = 8u;  }

    float4 a0 = make_float4(0.f, 0.f, 0.f, 0.f);
    float4 a1 = a0, b0 = a0, b1 = a0;
    const int estart = rs[le];
    const int eend = rs[le + 1];
    int e = estart + grp;
    for (; e + 6 < eend; e += 8) {
        unsigned p0 = spay[e], p1 = spay[e + 2], p2 = spay[e + 4], p3 = spay[e + 6];
        uint4 u0 = *(const uint4*)(ub + (size_t)(p0 & 0x3FFFFu) * scale);
        uint4 u1 = *(const uint4*)(ub + (size_t)(p1 & 0x3FFFFu) * scale);
        uint4 u2 = *(const uint4*)(ub + (size_t)(p2 & 0x3FFFFu) * scale);
        uint4 u3 = *(const uint4*)(ub + (size_t)(p3 & 0x3FFFFu) * scale);
        fma8(a0, a1, u0, (float)(p0 >> 18) * VS);
        fma8(b0, b1, u1, (float)(p1 >> 18) * VS);
        fma8(a0, a1, u2, (float)(p2 >> 18) * VS);
        fma8(b0, b1, u3, (float)(p3 >> 18) * VS);
    }
    for (; e < eend; e += 2) {
        unsigned p = spay[e];
        uint4 u = *(const uint4*)(ub + (size_t)(p & 0x3FFFFu) * scale);
        fma8(a0, a1, u, (float)(p >> 18) * VS);
    }
    a0.x += b0.x; a0.y += b0.y; a0.z += b0.z; a0.w += b0.w;
    a1.x += b1.x; a1.y += b1.y; a1.z += b1.z; a1.w += b1.w;

    // combine the two groups via LDS, then one RMW to out
    const int c2 = (q8 >> 2);  // 0,2,4,6,8
    __syncthreads();
    if (grp == 1) { red4[le][c2] = a0; red4[le][c2 + 1] = a1; }
    __syncthreads();
    if (grp == 0) {
        float4 r0 = red4[le][c2];
        float4 r1 = red4[le][c2 + 1];
        int gr = b * 64 + le;
        if (gr < Nn && eend > estart) {
            float* po = out + gr * 40 + q8;
            float4 o0 = *(const float4*)po;
            o0.x += a0.x + r0.x; o0.y += a0.y + r0.y;
            o0.z += a0.z + r0.z; o0.w += a0.w + r0.w;
            *(float4*)po = o0;
            float4 o1 = *(const float4*)(po + 4);
            o1.x += a1.x + r1.x; o1.y += a1.y + r1.y;
            o1.z += a1.z + r1.z; o1.w += a1.w + r1.w;
            *(float4*)(po + 4) = o1;
        }
    }
}

// Slow-path for (expected-tiny) bucket overflow.  Properly parallel grid.
__global__ __launch_bounds__(256) void ovf_scatter(
    const int* __restrict__ ovf_cnt, const unsigned* __restrict__ ovf,
    const unsigned short* __restrict__ gA, const unsigned short* __restrict__ gB,
    float* __restrict__ out) {
    int n = *ovf_cnt;
    n = (n < OVFCAP) ? n : OVFCAP;
    int total = n * 40;
    const int stride = gridDim.x * blockDim.x;
    for (int i = blockIdx.x * blockDim.x + threadIdx.x; i < total; i += stride) {
        int idx = i / 40, c = i % 40;
        unsigned s = ovf[3 * idx];
        unsigned p = ovf[3 * idx + 1];
        float v = __uint_as_float(ovf[3 * idx + 2]);
        unsigned rid = p & 0x3FFFFu;           // d | gbit<<17
        float gf = (c < 32) ? bf2f(gA[rid * 32u + c]) : bf2f(gB[rid * 8u + (c - 32)]);
        unsafeAtomicAdd(out + s * 40 + c, v * gf);
    }
}

extern "C" void kernel_launch(void* const* d_in, const int* in_sizes, int n_in,
                              void* d_out, int out_size, void* d_ws, size_t ws_size,
                              hipStream_t stream) {
    const float* x        = (const float*)d_in[0];
    const int*   adj_src  = (const int*)d_in[2];
    const int*   adj_dst  = (const int*)d_in[3];
    const float* adj_val  = (const float*)d_in[4];
    const int*   adj2_src = (const int*)d_in[5];
    const int*   adj2_dst = (const int*)d_in[6];
    const float* adj2_val = (const float*)d_in[7];
    const float* fc1_w    = (const float*)d_in[8];
    const float* fc_out_w = (const float*)d_in[9];
    const float* fc_out_b = (const float*)d_in[10];
    float* out = (float*)d_out;

    char* ws = (char*)d_ws;
    unsigned short* Mb      = (unsigned short*)(ws + MP_OFF);
    unsigned short* gA      = (unsigned short*)(ws + GA_OFF);
    unsigned short* gB      = (unsigned short*)(ws + GB_OFF);
    int*            gcur    = (int*)(ws + GCUR_OFF);
    int*            ovf_cnt = (int*)(ws + OVFC_OFF);
    unsigned*       ovf     = (unsigned*)(ws + OVFL_OFF);
    uint2*          payload = (uint2*)(ws + PAY_OFF);

    const int E1 = in_sizes[2];
    const int E2 = in_sizes[5];
    const int Etot = E1 + E2;

    make_M<<<128, 256, 0, stream>>>(fc1_w, fc_out_w, Mb);
    gemm_mfma<<<(Nn + 127) / 128, 512, 0, stream>>>(x, Mb, fc_out_b, out, gA, gB);

    hipMemsetAsync(gcur, 0, (OVFC_OFF - GCUR_OFF) + 16, stream);  // gcur + ovf_cnt
    partition<<<(Etot + CHUNK - 1) / CHUNK, 1024, 0, stream>>>(
        adj_src, adj_dst, adj_val, E1, adj2_src, adj2_dst, adj2_val, E2,
        gcur, payload, ovf_cnt, ovf);
    bucket_gather<<<NB, 640, 0, stream>>>(gcur, payload, gA, gB, out);
    ovf_scatter<<<512, 256, 0, stream>>>(ovf_cnt, ovf, gA, gB, out);
}